// Round 8
// baseline (2945.437 us; speedup 1.0000x reference)
//
#include <hip/hip_runtime.h>
#include <hip/hip_bf16.h>

// ---------------------------------------------------------------------------
// Encoder: emb gather -> LSTM0 -> LSTM1 -> BatchNorm(inference)
// B=64, T=128, D=256, H=1024, 4H=4096, BT=8192 rows.
//
// Round-8 structure:
//  - XW = x@W precomputed by GEMMs (plain row-major A buffers).
//  - Recurrence: persistent plain-launch <<<256,256>>> (1 WG/CU, 18KB LDS).
//    WG = 32 rows x 32 pc. Wave = K-quarter of the WG's single 32x32 tile.
//    U lives in REGISTERS (64 VGPR/lane, loaded once/layer). A (h) loaded
//    straight global->reg each step: 16 back-to-back dwordx4 loads, one
//    natural vmcnt pipeline (r7 lesson: interleaved shallow groups serialize
//    on latency). MFMAs are pure-register. 4 s_barriers/step (r6 had 13).
//  - hall[t] slots plain row-major; writers use agent-scope atomic stores
//    (proven r6/r7); readers normal cached loads.
//  - Grid barrier: vmcnt(0) + relaxed agent atomicAdd + spin (r2: grid.sync
//    ~30us/step).
// ---------------------------------------------------------------------------

typedef __attribute__((ext_vector_type(8))) short short8;
typedef __attribute__((ext_vector_type(4))) short short4v;
typedef __attribute__((ext_vector_type(4))) float f32x4;
typedef __attribute__((ext_vector_type(16))) float f32x16;
typedef unsigned short ushort_t;

__device__ __forceinline__ void lgkm0_bar() {
  asm volatile("s_waitcnt lgkmcnt(0)" ::: "memory");
  __builtin_amdgcn_s_barrier();
}

__device__ __forceinline__ ushort_t f2b(float f) {
  __hip_bfloat16 h = __float2bfloat16(f);
  return *reinterpret_cast<ushort_t*>(&h);
}
__device__ __forceinline__ float b2f(ushort_t u) {
  unsigned int x = ((unsigned int)u) << 16;
  return __builtin_bit_cast(float, x);
}
__device__ __forceinline__ float fsigmoid(float x) {
  return 1.f / (1.f + __expf(-x));
}
__device__ __forceinline__ float ftanh(float x) {
  return 1.f - 2.f / (__expf(2.f * x) + 1.f);
}

__device__ __forceinline__ void gload_lds16(const ushort_t* g, ushort_t* l) {
  __builtin_amdgcn_global_load_lds(
      (const __attribute__((address_space(1))) unsigned int*)g,
      (__attribute__((address_space(3))) unsigned int*)l, 16, 0, 0);
}

// ---- convert W [K][4096] f32 -> [pc][k] bf16 (GEMM B-operand) -------------
__global__ __launch_bounds__(256) void k_convert(
    const float* __restrict__ src, ushort_t* __restrict__ dst, int kshift) {
  size_t tid = (size_t)blockIdx.x * 256 + threadIdx.x;  // = k*4096 + c
  int k = (int)(tid >> 12);
  int c = (int)(tid & 4095);
  int pc = ((c & 1023) << 2) | (c >> 10);
  dst[((size_t)pc << kshift) + k] = f2b(src[tid]);
}

// ---- convert U [1024][4096] f32 -> per-wave register-frag order -----------
// chunk cid = (((ws*4 + kh)*16 + ks)*64 + l):
//   pc = ws*32 + (l&31), k = kh*256 + ks*16 + (l>>5)*8 + e
__global__ __launch_bounds__(256) void k_convert_u(
    const float* __restrict__ src, ushort_t* __restrict__ dst) {
  int cid = blockIdx.x * 256 + threadIdx.x;
  int l = cid & 63;
  int ks = (cid >> 6) & 15;
  int kh = (cid >> 10) & 3;
  int ws = cid >> 12;                       // 0..127
  int pc = ws * 32 + (l & 31);
  int c = ((pc & 3) << 10) | (pc >> 2);
  int k0 = kh * 256 + ks * 16 + (l >> 5) * 8;
  short8 v;
#pragma unroll
  for (int e = 0; e < 8; ++e)
    v[e] = (short)f2b(src[(size_t)(k0 + e) * 4096 + c]);
  *(short8*)(dst + (size_t)cid * 8) = v;
}

// ---- permute biases -------------------------------------------------------
__global__ __launch_bounds__(256) void k_bias(
    const float* __restrict__ b0, const float* __restrict__ b1,
    float* __restrict__ bp0, float* __restrict__ bp1) {
  int pc = blockIdx.x * 256 + threadIdx.x;
  int c = ((pc & 3) << 10) | (pc >> 2);
  bp0[pc] = b0[c];
  bp1[pc] = b1[c];
}

// ---- embedding gather: plain row-major Xef[8192][256] ---------------------
__global__ __launch_bounds__(256) void k_gather(
    const int* __restrict__ tokens, const float* __restrict__ emb,
    ushort_t* __restrict__ Xef) {
  int row = blockIdx.x;            // row = t*64 + b
  int t = row >> 6, b = row & 63;
  int tok = tokens[b * 128 + t];
  int d = threadIdx.x;
  Xef[(size_t)row * 256 + d] = f2b(emb[(size_t)tok * 256 + d]);
}

// ---- state init: h0 -> hall slot0 (plain); c0 -> c_st; zero barriers ------
__global__ __launch_bounds__(256) void k_init(
    const float* __restrict__ h0, const float* __restrict__ c0,
    ushort_t* __restrict__ hall, float* __restrict__ c_st,
    unsigned* __restrict__ bars) {
  int tid = blockIdx.x * 256 + threadIdx.x;
  c_st[tid] = c0[tid];
  hall[tid] = f2b(h0[tid]);
  if (tid < 2) bars[tid] = 0;
}

// ---- GEMM: C[8192][4096] = A[8192][K] * BT[4096][K]^T ---------------------
// A plain row-major (LAY=0: Xef [8192][256]; LAY=1: hall slots 1..128).
// 128x128 tile, global_load_lds staging, XCD-blocked (8 wgM inner, wgN outer).
template <int NKS, int LAY>
__global__ __launch_bounds__(256) void k_gemm(
    const ushort_t* __restrict__ Af, const ushort_t* __restrict__ BT,
    ushort_t* __restrict__ C) {
  const int K = NKS * 16;
  const int xcd = blockIdx.x & 7, loc = blockIdx.x >> 3;
  const int wgM = xcd * 8 + (loc & 7);
  const int wgN = loc >> 3;
  const int tid = threadIdx.x;
  const int l = tid & 63;
  const int wv = tid >> 6;
  const int wvM = wv & 1, wvN = wv >> 1;

  __shared__ __align__(16) ushort_t Alds[4096];
  __shared__ __align__(16) ushort_t Blds[4096];

  const int m0 = wgM * 128, n0 = wgN * 128;
  f32x4 acc[4][4] = {};

  for (int k0 = 0; k0 < K; k0 += 32) {
    __syncthreads();
#pragma unroll
    for (int jj = 0; jj < 2; ++jj) {
      int c = jj * 256 + tid;
      int kc = c >> 7, r = c & 127;
      int R = m0 + r;
      int kcg = (k0 >> 3) + kc;
      const ushort_t* asrc =
          (LAY == 0) ? (Af + (size_t)R * 256 + kcg * 8)
                     : (Af + (size_t)(R >> 6) * 65536 + (R & 63) * 1024 + kcg * 8);
      gload_lds16(asrc, (ushort_t*)&Alds[(size_t)(jj * 256 + (tid & ~63)) * 8]);
      gload_lds16(BT + (size_t)(n0 + r) * K + k0 + kc * 8,
                  (ushort_t*)&Blds[(size_t)(jj * 256 + (tid & ~63)) * 8]);
    }
    __syncthreads();

    short8 af[4], bf[4];
#pragma unroll
    for (int mt = 0; mt < 4; ++mt)
      af[mt] = *(const short8*)&Alds[((l >> 4) * 128 + wvM * 64 + mt * 16 + (l & 15)) * 8];
#pragma unroll
    for (int nt = 0; nt < 4; ++nt)
      bf[nt] = *(const short8*)&Blds[((l >> 4) * 128 + wvN * 64 + nt * 16 + (l & 15)) * 8];
#pragma unroll
    for (int mt = 0; mt < 4; ++mt)
#pragma unroll
      for (int nt = 0; nt < 4; ++nt)
        acc[mt][nt] =
            __builtin_amdgcn_mfma_f32_16x16x32_bf16(af[mt], bf[nt], acc[mt][nt], 0, 0, 0);
  }

  const int rr0 = wgM * 128 + wvM * 64 + (l >> 4) * 4;
  const int cc0 = wgN * 128 + wvN * 64 + (l & 15);
#pragma unroll
  for (int mt = 0; mt < 4; ++mt)
#pragma unroll
    for (int nt = 0; nt < 4; ++nt)
#pragma unroll
      for (int r = 0; r < 4; ++r)
        C[(size_t)(rr0 + mt * 16 + r) * 4096 + cc0 + nt * 16] =
            f2b(acc[mt][nt][r]);
}

// ---- persistent LSTM layer (128 steps), plain launch <<<256,256>>> --------
// WG (ws = pc-slice of 32, g = row-half of 32). Wave kh = K-quarter of the
// WG's 32x32 output tile; U-quarter in 64 VGPRs, A global->reg, MFMA in regs.
template <int LAYER>
__global__ __launch_bounds__(256, 1) void k_pers(
    const ushort_t* __restrict__ Uf,    // register-frag order (k_convert_u)
    const ushort_t* __restrict__ XW,    // [8192][4096] bf16 row-major
    const float* __restrict__ bp,       // [4096] permuted bias
    ushort_t* __restrict__ hall,        // 129 slots x [64][1024] bf16
    float* __restrict__ c_st,           // [64][1024] f32
    float* __restrict__ outp,           // L1: d_out
    const float* __restrict__ gamma, const float* __restrict__ beta,
    const float* __restrict__ mean, const float* __restrict__ var,
    unsigned* __restrict__ bar) {
  const int bid = blockIdx.x;
  const int xcd = bid & 7, loc = bid >> 3;
  const int ws = xcd * 16 + (loc & 15);   // pc-slice 0..127 (32 pc = 8 j)
  const int g = loc >> 4;                 // row half 0..1
  const int tid = threadIdx.x;
  const int l = tid & 63;
  const int kh = tid >> 6;                // wave = K-quarter

  __shared__ float zls[4][32][33];        // 16.9 KB K-reduce
  __shared__ ushort_t hbuf[32][8];        // 512 B h assembly

  // ---- U-quarter -> 64 VGPRs (contiguous stream, once per layer) ----
  short8 ur[16];
  {
    const ushort_t* ub = Uf + ((size_t)((ws * 4 + kh) * 16) * 64 + l) * 8;
#pragma unroll
    for (int ks = 0; ks < 16; ++ks)
      ur[ks] = *(const short8*)(ub + (size_t)ks * 512);
  }

  // ---- epilogue constants: thread owns (row_o, j_o) ----
  const int row_o = tid & 31, j_o = tid >> 5;   // j_o 0..7
  const int rowg = g * 32 + row_o;
  const int j = ws * 8 + j_o;
  float creg = c_st[rowg * 1024 + j];
  const f32x4 bias_v = *(const f32x4*)(bp + ws * 32 + j_o * 4);
  float scl = 0.f, sft = 0.f;
  if (LAYER == 1) {
    float inv = rsqrtf(var[j] + 1e-3f);
    scl = inv * gamma[j];
    sft = beta[j] - mean[j] * scl;
  }

#pragma unroll 1
  for (int t = 0; t < 128; ++t) {
    const ushort_t* hin =
        hall + (size_t)((LAYER == 1 && t == 0) ? 128 : t) * 65536;
    ushort_t* hout = hall + (size_t)(t + 1) * 65536;

    // ---- A: 16 back-to-back 16B loads (row = g*32 + (l&31)) ----
    const ushort_t* ab =
        hin + (size_t)(g * 32 + (l & 31)) * 1024 + kh * 256 + (l >> 5) * 8;
    short8 ar[16];
#pragma unroll
    for (int ks = 0; ks < 16; ++ks)
      ar[ks] = *(const short8*)(ab + ks * 16);

    // ---- XW prefetch (consumed in epilogue) ----
    short4v xw = *(const short4v*)(
        XW + ((size_t)(t * 64 + rowg) << 12) + ws * 32 + j_o * 4);

    // ---- 16 register-only MFMAs (4 chains) ----
    f32x16 acc0 = {}, acc1 = {}, acc2 = {}, acc3 = {};
#pragma unroll
    for (int ks = 0; ks < 16; ks += 4) {
      acc0 = __builtin_amdgcn_mfma_f32_32x32x16_bf16(ar[ks + 0], ur[ks + 0], acc0, 0, 0, 0);
      acc1 = __builtin_amdgcn_mfma_f32_32x32x16_bf16(ar[ks + 1], ur[ks + 1], acc1, 0, 0, 0);
      acc2 = __builtin_amdgcn_mfma_f32_32x32x16_bf16(ar[ks + 2], ur[ks + 2], acc2, 0, 0, 0);
      acc3 = __builtin_amdgcn_mfma_f32_32x32x16_bf16(ar[ks + 3], ur[ks + 3], acc3, 0, 0, 0);
    }
    f32x16 zt = (acc0 + acc1) + (acc2 + acc3);

    // ---- K-partials to LDS (32x32 C layout) ----
#pragma unroll
    for (int r = 0; r < 16; ++r)
      zls[kh][(r & 3) + 8 * (r >> 2) + 4 * (l >> 5)][l & 31] = zt[r];
    lgkm0_bar();

    // ---- epilogue: 4-way K-sum, gates, c-update, BN ----
    float z4[4];
#pragma unroll
    for (int gi = 0; gi < 4; ++gi) {
      int c = j_o * 4 + gi;
      z4[gi] = ((zls[0][row_o][c] + zls[1][row_o][c]) +
                (zls[2][row_o][c] + zls[3][row_o][c])) +
               b2f((ushort_t)xw[gi]) + bias_v[gi];
    }
    float ii = fsigmoid(z4[0]), ff = fsigmoid(z4[1]);
    float gg = ftanh(z4[2]), oo = fsigmoid(z4[3]);
    creg = ff * creg + ii * gg;
    float hn = oo * ftanh(creg);
    hbuf[row_o][j_o] = f2b(hn);
    if (LAYER == 1) {
      outp[((size_t)rowg * 128 + t) * 1024 + j] = hn * scl + sft;
      if (t == 127) {
        outp[8388608 + rowg * 1024 + j] = hn;
        outp[8454144 + rowg * 1024 + j] = creg;
      }
    } else if (t == 127) {
      c_st[rowg * 1024 + j] = creg;
    }
    lgkm0_bar();   // hbuf ready; zls reads done before next overwrite

    // ---- h out: 32 threads x 16B, agent-scope (cross-XCD visible) ----
    if (tid < 32) {
      short8 v = *(const short8*)&hbuf[tid][0];
      union { short8 s; unsigned u[4]; } cv;
      cv.s = v;
      unsigned* dst = (unsigned*)(hout + (size_t)(g * 32 + tid) * 1024 + ws * 8);
#pragma unroll
      for (int wi = 0; wi < 4; ++wi)
        __hip_atomic_store(dst + wi, cv.u[wi], __ATOMIC_RELAXED,
                           __HIP_MEMORY_SCOPE_AGENT);
    }

    // ---- grid barrier: drain stores, arrive, spin ----
    asm volatile("s_waitcnt vmcnt(0)" ::: "memory");
    __builtin_amdgcn_s_barrier();
    if (tid == 0) {
      __hip_atomic_fetch_add(bar, 1u, __ATOMIC_RELAXED,
                             __HIP_MEMORY_SCOPE_AGENT);
      unsigned tg = 256u * (unsigned)(t + 1);
      while (__hip_atomic_load(bar, __ATOMIC_RELAXED,
                               __HIP_MEMORY_SCOPE_AGENT) < tg)
        __builtin_amdgcn_s_sleep(2);
    }
    __builtin_amdgcn_s_barrier();
  }
}

extern "C" void kernel_launch(void* const* d_in, const int* in_sizes, int n_in,
                              void* d_out, int out_size, void* d_ws,
                              size_t ws_size, hipStream_t stream) {
  const int* tokens = (const int*)d_in[0];
  const float* h0 = (const float*)d_in[1];
  const float* c0 = (const float*)d_in[2];
  const float* emb = (const float*)d_in[3];
  const float* W0 = (const float*)d_in[4];
  const float* U0 = (const float*)d_in[5];
  const float* b0 = (const float*)d_in[6];
  const float* W1 = (const float*)d_in[7];
  const float* U1 = (const float*)d_in[8];
  const float* b1 = (const float*)d_in[9];
  const float* gammap = (const float*)d_in[10];
  const float* betap = (const float*)d_in[11];
  const float* mmean = (const float*)d_in[12];
  const float* mvar = (const float*)d_in[13];

  char* ws = (char*)d_ws;
  ushort_t* Uc0 = (ushort_t*)(ws + 0);             //  8 MB reg-frag U0
  ushort_t* Uc1 = (ushort_t*)(ws + 8388608);       //  8 MB reg-frag U1
  ushort_t* W0f = (ushort_t*)(ws + 16777216);      //  2 MB [pc][256]
  ushort_t* W1f = (ushort_t*)(ws + 18874368);      //  8 MB [pc][1024]
  float* bp0 = (float*)(ws + 27262976);            // 16 KB
  float* bp1 = (float*)(ws + 27279360);            // 16 KB
  ushort_t* Xef = (ushort_t*)(ws + 27295744);      //  4 MB [8192][256]
  ushort_t* XW = (ushort_t*)(ws + 31490048);       // 64 MB [8192][4096]
  ushort_t* hall = (ushort_t*)(ws + 98598912);     // 16.5 MB: 129 x 128KB
  float* c_st = (float*)(ws + 115507200);          // 256 KB
  unsigned* bars = (unsigned*)(ws + 115769344);    // 8 B

  k_convert_u<<<2048, 256, 0, stream>>>(U0, Uc0);
  k_convert_u<<<2048, 256, 0, stream>>>(U1, Uc1);
  k_convert<<<4096, 256, 0, stream>>>(W0, W0f, 8);
  k_convert<<<16384, 256, 0, stream>>>(W1, W1f, 10);
  k_bias<<<16, 256, 0, stream>>>(b0, b1, bp0, bp1);
  k_gather<<<8192, 256, 0, stream>>>(tokens, emb, Xef);
  k_init<<<256, 256, 0, stream>>>(h0, c0, hall, c_st, bars);

  float* outp = (float*)d_out;

  // ---- layer 0 ----
  k_gemm<16, 0><<<2048, 256, 0, stream>>>(Xef, W0f, XW);
  k_pers<0><<<256, 256, 0, stream>>>(Uc0, XW, bp0, hall, c_st, nullptr,
                                     nullptr, nullptr, nullptr, nullptr,
                                     bars + 0);

  // ---- layer 1 (GEMM A = hall slots 1..128 = L0 outputs) ----
  k_gemm<64, 1><<<2048, 256, 0, stream>>>(hall + 65536, W1f, XW);
  k_pers<1><<<256, 256, 0, stream>>>(Uc1, XW, bp1, hall, c_st, outp, gammap,
                                     betap, mmean, mvar, bars + 1);
}

// Round 9
// 1773.238 us; speedup vs baseline: 1.6611x; 1.6611x over previous
//
#include <hip/hip_runtime.h>
#include <hip/hip_bf16.h>

// ---------------------------------------------------------------------------
// Encoder: emb gather -> LSTM0 -> LSTM1 -> BatchNorm(inference)
// B=64, T=128, D=256, H=1024, 4H=4096, BT=8192 rows.
//
// Round-9 structure:
//  - XW = x@W precomputed by GEMMs (plain row-major A buffers).
//  - Recurrence: persistent plain-launch <<<256,256>>> (1 WG/CU, 82KB LDS).
//    WG = 32 rows x 32 pc; wave = K-quarter. U slice in LDS (64KB; r8 lesson:
//    asm "memory" clobbers force global re-loads every iteration -> registers
//    can't hold U; LDS residency is guaranteed). A (h) loaded global->reg,
//    16 back-to-back 16B loads; MFMA: A from reg, B from LDS (conflict-free
//    1KB-contiguous ds_read_b128).
//  - Row-halves g=0/1 are INDEPENDENT subgrids (no data exchange) -> separate
//    barrier trees. XCD-mapping: g = xcd&1, so each XCD touches one 32-row
//    h block (L2-shared by its 32 WGs) and its 2MB of U stays L2-resident.
//  - Tree barrier (r8 lesson: flat 256-WG atomic counter serializes):
//    per-XCD group ctr (32 adds, 8 lines in parallel) -> per-g root (4 adds)
//    -> tid0 polls root; still relaxed agent atomics + vmcnt(0) drain only.
//  - hall[t] slots row-major; agent-scope atomic stores (proven r6-r8);
//    readers first-touch slot lines in-kernel only after the write.
// ---------------------------------------------------------------------------

typedef __attribute__((ext_vector_type(8))) short short8;
typedef __attribute__((ext_vector_type(4))) short short4v;
typedef __attribute__((ext_vector_type(4))) float f32x4;
typedef __attribute__((ext_vector_type(16))) float f32x16;
typedef unsigned short ushort_t;

__device__ __forceinline__ void lgkm0_bar() {
  asm volatile("s_waitcnt lgkmcnt(0)" ::: "memory");
  __builtin_amdgcn_s_barrier();
}

__device__ __forceinline__ ushort_t f2b(float f) {
  __hip_bfloat16 h = __float2bfloat16(f);
  return *reinterpret_cast<ushort_t*>(&h);
}
__device__ __forceinline__ float b2f(ushort_t u) {
  unsigned int x = ((unsigned int)u) << 16;
  return __builtin_bit_cast(float, x);
}
__device__ __forceinline__ float fsigmoid(float x) {
  return 1.f / (1.f + __expf(-x));
}
__device__ __forceinline__ float ftanh(float x) {
  return 1.f - 2.f / (__expf(2.f * x) + 1.f);
}

__device__ __forceinline__ void gload_lds16(const ushort_t* g, ushort_t* l) {
  __builtin_amdgcn_global_load_lds(
      (const __attribute__((address_space(1))) unsigned int*)g,
      (__attribute__((address_space(3))) unsigned int*)l, 16, 0, 0);
}

// ---- convert W [K][4096] f32 -> [pc][k] bf16 (GEMM B-operand) -------------
__global__ __launch_bounds__(256) void k_convert(
    const float* __restrict__ src, ushort_t* __restrict__ dst, int kshift) {
  size_t tid = (size_t)blockIdx.x * 256 + threadIdx.x;  // = k*4096 + c
  int k = (int)(tid >> 12);
  int c = (int)(tid & 4095);
  int pc = ((c & 1023) << 2) | (c >> 10);
  dst[((size_t)pc << kshift) + k] = f2b(src[tid]);
}

// ---- convert U [1024][4096] f32 -> per-slice MFMA-frag order --------------
// chunk cid = (((ws*4 + kh)*16 + ks)*64 + l):
//   pc = ws*32 + (l&31), k = kh*256 + ks*16 + (l>>5)*8 + e
__global__ __launch_bounds__(256) void k_convert_u(
    const float* __restrict__ src, ushort_t* __restrict__ dst) {
  int cid = blockIdx.x * 256 + threadIdx.x;
  int l = cid & 63;
  int ks = (cid >> 6) & 15;
  int kh = (cid >> 10) & 3;
  int ws = cid >> 12;                       // 0..127
  int pc = ws * 32 + (l & 31);
  int c = ((pc & 3) << 10) | (pc >> 2);
  int k0 = kh * 256 + ks * 16 + (l >> 5) * 8;
  short8 v;
#pragma unroll
  for (int e = 0; e < 8; ++e)
    v[e] = (short)f2b(src[(size_t)(k0 + e) * 4096 + c]);
  *(short8*)(dst + (size_t)cid * 8) = v;
}

// ---- permute biases -------------------------------------------------------
__global__ __launch_bounds__(256) void k_bias(
    const float* __restrict__ b0, const float* __restrict__ b1,
    float* __restrict__ bp0, float* __restrict__ bp1) {
  int pc = blockIdx.x * 256 + threadIdx.x;
  int c = ((pc & 3) << 10) | (pc >> 2);
  bp0[pc] = b0[c];
  bp1[pc] = b1[c];
}

// ---- embedding gather: plain row-major Xef[8192][256] ---------------------
__global__ __launch_bounds__(256) void k_gather(
    const int* __restrict__ tokens, const float* __restrict__ emb,
    ushort_t* __restrict__ Xef) {
  int row = blockIdx.x;            // row = t*64 + b
  int t = row >> 6, b = row & 63;
  int tok = tokens[b * 128 + t];
  int d = threadIdx.x;
  Xef[(size_t)row * 256 + d] = f2b(emb[(size_t)tok * 256 + d]);
}

// ---- state init: h0 -> hall slot0 (plain); c0 -> c_st; zero barriers ------
__global__ __launch_bounds__(256) void k_init(
    const float* __restrict__ h0, const float* __restrict__ c0,
    ushort_t* __restrict__ hall, float* __restrict__ c_st,
    unsigned* __restrict__ bars) {
  int tid = blockIdx.x * 256 + threadIdx.x;
  c_st[tid] = c0[tid];
  hall[tid] = f2b(h0[tid]);
  if (tid < 512) bars[tid] = 0;
}

// ---- GEMM: C[8192][4096] = A[8192][K] * BT[4096][K]^T ---------------------
// A plain row-major (LAY=0: Xef [8192][256]; LAY=1: hall slots 1..128).
// 128x128 tile, global_load_lds staging, XCD-blocked (8 wgM inner, wgN outer).
template <int NKS, int LAY>
__global__ __launch_bounds__(256) void k_gemm(
    const ushort_t* __restrict__ Af, const ushort_t* __restrict__ BT,
    ushort_t* __restrict__ C) {
  const int K = NKS * 16;
  const int xcd = blockIdx.x & 7, loc = blockIdx.x >> 3;
  const int wgM = xcd * 8 + (loc & 7);
  const int wgN = loc >> 3;
  const int tid = threadIdx.x;
  const int l = tid & 63;
  const int wv = tid >> 6;
  const int wvM = wv & 1, wvN = wv >> 1;

  __shared__ __align__(16) ushort_t Alds[4096];
  __shared__ __align__(16) ushort_t Blds[4096];

  const int m0 = wgM * 128, n0 = wgN * 128;
  f32x4 acc[4][4] = {};

  for (int k0 = 0; k0 < K; k0 += 32) {
    __syncthreads();
#pragma unroll
    for (int jj = 0; jj < 2; ++jj) {
      int c = jj * 256 + tid;
      int kc = c >> 7, r = c & 127;
      int R = m0 + r;
      int kcg = (k0 >> 3) + kc;
      const ushort_t* asrc =
          (LAY == 0) ? (Af + (size_t)R * 256 + kcg * 8)
                     : (Af + (size_t)(R >> 6) * 65536 + (R & 63) * 1024 + kcg * 8);
      gload_lds16(asrc, (ushort_t*)&Alds[(size_t)(jj * 256 + (tid & ~63)) * 8]);
      gload_lds16(BT + (size_t)(n0 + r) * K + k0 + kc * 8,
                  (ushort_t*)&Blds[(size_t)(jj * 256 + (tid & ~63)) * 8]);
    }
    __syncthreads();

    short8 af[4], bf[4];
#pragma unroll
    for (int mt = 0; mt < 4; ++mt)
      af[mt] = *(const short8*)&Alds[((l >> 4) * 128 + wvM * 64 + mt * 16 + (l & 15)) * 8];
#pragma unroll
    for (int nt = 0; nt < 4; ++nt)
      bf[nt] = *(const short8*)&Blds[((l >> 4) * 128 + wvN * 64 + nt * 16 + (l & 15)) * 8];
#pragma unroll
    for (int mt = 0; mt < 4; ++mt)
#pragma unroll
      for (int nt = 0; nt < 4; ++nt)
        acc[mt][nt] =
            __builtin_amdgcn_mfma_f32_16x16x32_bf16(af[mt], bf[nt], acc[mt][nt], 0, 0, 0);
  }

  const int rr0 = wgM * 128 + wvM * 64 + (l >> 4) * 4;
  const int cc0 = wgN * 128 + wvN * 64 + (l & 15);
#pragma unroll
  for (int mt = 0; mt < 4; ++mt)
#pragma unroll
    for (int nt = 0; nt < 4; ++nt)
#pragma unroll
      for (int r = 0; r < 4; ++r)
        C[(size_t)(rr0 + mt * 16 + r) * 4096 + cc0 + nt * 16] =
            f2b(acc[mt][nt][r]);
}

// ---- persistent LSTM layer (128 steps), plain launch <<<256,256>>> --------
// bid -> xcd = bid&7, g = xcd&1 (row half), ws = (xcd>>1)*32 + bid>>3.
// WG: rows [g*32,+32) x pc [ws*32,+32). Wave kh = K-quarter; U from LDS,
// A from registers (16 back-to-back global loads per step).
template <int LAYER>
__global__ __launch_bounds__(256, 1) void k_pers(
    const ushort_t* __restrict__ Uf,    // slice-frag order (k_convert_u)
    const ushort_t* __restrict__ XW,    // [8192][4096] bf16 row-major
    const float* __restrict__ bp,       // [4096] permuted bias
    ushort_t* __restrict__ hall,        // 129 slots x [64][1024] bf16
    float* __restrict__ c_st,           // [64][1024] f32
    float* __restrict__ outp,           // L1: d_out
    const float* __restrict__ gamma, const float* __restrict__ beta,
    const float* __restrict__ mean, const float* __restrict__ var,
    unsigned* __restrict__ bar) {
  const int bid = blockIdx.x;
  const int xcd = bid & 7;
  const int g = xcd & 1;                  // row half (independent subgrid)
  const int ws = (xcd >> 1) * 32 + (bid >> 3);   // pc-slice 0..127
  const int tid = threadIdx.x;
  const int l = tid & 63;
  const int kh = tid >> 6;                // wave = K-quarter

  __shared__ __align__(16) ushort_t Ulds[32768];   // 64 KB U slice
  __shared__ float zls[4][32][33];                 // 16.9 KB K-reduce
  __shared__ ushort_t hbuf[32][8];                 // 512 B h assembly

  // ---- stage U slice into LDS (4096 x 16B, coalesced) ----
  {
    const ushort_t* src = Uf + (size_t)ws * 32768;
    for (int i = tid; i < 4096; i += 256)
      *(short8*)(Ulds + (size_t)i * 8) = *(const short8*)(src + (size_t)i * 8);
  }

  // ---- epilogue constants: thread owns (row_o, j_o) ----
  const int row_o = tid & 31, j_o = tid >> 5;   // j_o 0..7
  const int rowg = g * 32 + row_o;
  const int j = ws * 8 + j_o;
  float creg = c_st[rowg * 1024 + j];
  const f32x4 bias_v = *(const f32x4*)(bp + ws * 32 + j_o * 4);
  float scl = 0.f, sft = 0.f;
  if (LAYER == 1) {
    float inv = rsqrtf(var[j] + 1e-3f);
    scl = inv * gamma[j];
    sft = beta[j] - mean[j] * scl;
  }

  unsigned* grp = bar + xcd * 16;          // per-XCD counter line
  unsigned* root = bar + 128 + g * 16;     // per-half root
  const bool leader = (bid >> 3) == 0;     // one WG per XCD

  __syncthreads();   // Ulds visible

#pragma unroll 1
  for (int t = 0; t < 128; ++t) {
    const ushort_t* hin =
        hall + (size_t)((LAYER == 1 && t == 0) ? 128 : t) * 65536;
    ushort_t* hout = hall + (size_t)(t + 1) * 65536;

    // ---- A: 16 back-to-back 16B loads (row = g*32 + (l&31)) ----
    const ushort_t* ab =
        hin + (size_t)(g * 32 + (l & 31)) * 1024 + kh * 256 + (l >> 5) * 8;
    short8 ar[16];
#pragma unroll
    for (int ks = 0; ks < 16; ++ks)
      ar[ks] = *(const short8*)(ab + ks * 16);

    // ---- XW prefetch (consumed in epilogue) ----
    short4v xw = *(const short4v*)(
        XW + ((size_t)(t * 64 + rowg) << 12) + ws * 32 + j_o * 4);

    // ---- 16 MFMAs: A reg, B from LDS (1KB-contiguous ds_read_b128) ----
    const ushort_t* uB = Ulds + (size_t)kh * 8192;
    f32x16 acc0 = {}, acc1 = {}, acc2 = {}, acc3 = {};
#pragma unroll
    for (int ks = 0; ks < 16; ks += 4) {
      short8 b0 = *(const short8*)(uB + (size_t)(ks + 0) * 512 + l * 8);
      short8 b1 = *(const short8*)(uB + (size_t)(ks + 1) * 512 + l * 8);
      short8 b2 = *(const short8*)(uB + (size_t)(ks + 2) * 512 + l * 8);
      short8 b3 = *(const short8*)(uB + (size_t)(ks + 3) * 512 + l * 8);
      acc0 = __builtin_amdgcn_mfma_f32_32x32x16_bf16(ar[ks + 0], b0, acc0, 0, 0, 0);
      acc1 = __builtin_amdgcn_mfma_f32_32x32x16_bf16(ar[ks + 1], b1, acc1, 0, 0, 0);
      acc2 = __builtin_amdgcn_mfma_f32_32x32x16_bf16(ar[ks + 2], b2, acc2, 0, 0, 0);
      acc3 = __builtin_amdgcn_mfma_f32_32x32x16_bf16(ar[ks + 3], b3, acc3, 0, 0, 0);
    }
    f32x16 zt = (acc0 + acc1) + (acc2 + acc3);

    // ---- K-partials to LDS (32x32 C layout) ----
#pragma unroll
    for (int r = 0; r < 16; ++r)
      zls[kh][(r & 3) + 8 * (r >> 2) + 4 * (l >> 5)][l & 31] = zt[r];
    lgkm0_bar();

    // ---- epilogue: 4-way K-sum, gates, c-update, BN ----
    float z4[4];
#pragma unroll
    for (int gi = 0; gi < 4; ++gi) {
      int c = j_o * 4 + gi;
      z4[gi] = ((zls[0][row_o][c] + zls[1][row_o][c]) +
                (zls[2][row_o][c] + zls[3][row_o][c])) +
               b2f((ushort_t)xw[gi]) + bias_v[gi];
    }
    float ii = fsigmoid(z4[0]), ff = fsigmoid(z4[1]);
    float gg = ftanh(z4[2]), oo = fsigmoid(z4[3]);
    creg = ff * creg + ii * gg;
    float hn = oo * ftanh(creg);
    hbuf[row_o][j_o] = f2b(hn);
    if (LAYER == 1) {
      outp[((size_t)rowg * 128 + t) * 1024 + j] = hn * scl + sft;
      if (t == 127) {
        outp[8388608 + rowg * 1024 + j] = hn;
        outp[8454144 + rowg * 1024 + j] = creg;
      }
    } else if (t == 127) {
      c_st[rowg * 1024 + j] = creg;
    }
    lgkm0_bar();   // hbuf ready; zls reads done before next overwrite

    // ---- h out: 32 threads x 16B, agent-scope (cross-XCD visible) ----
    if (tid < 32) {
      short8 v = *(const short8*)&hbuf[tid][0];
      union { short8 s; unsigned u[4]; } cv;
      cv.s = v;
      unsigned* dst = (unsigned*)(hout + (size_t)(g * 32 + tid) * 1024 + ws * 8);
#pragma unroll
      for (int wi = 0; wi < 4; ++wi)
        __hip_atomic_store(dst + wi, cv.u[wi], __ATOMIC_RELAXED,
                           __HIP_MEMORY_SCOPE_AGENT);
    }

    // ---- tree barrier: drain stores; grp add (32/XCD) -> root (4/half) ----
    asm volatile("s_waitcnt vmcnt(0)" ::: "memory");
    __builtin_amdgcn_s_barrier();
    if (tid == 0) {
      __hip_atomic_fetch_add(grp, 1u, __ATOMIC_RELAXED,
                             __HIP_MEMORY_SCOPE_AGENT);
      if (leader) {
        unsigned tg = 32u * (unsigned)(t + 1);
        while (__hip_atomic_load(grp, __ATOMIC_RELAXED,
                                 __HIP_MEMORY_SCOPE_AGENT) < tg)
          __builtin_amdgcn_s_sleep(1);
        __hip_atomic_fetch_add(root, 1u, __ATOMIC_RELAXED,
                               __HIP_MEMORY_SCOPE_AGENT);
      }
      unsigned tr = 4u * (unsigned)(t + 1);
      while (__hip_atomic_load(root, __ATOMIC_RELAXED,
                               __HIP_MEMORY_SCOPE_AGENT) < tr)
        __builtin_amdgcn_s_sleep(1);
    }
    __builtin_amdgcn_s_barrier();
  }
}

extern "C" void kernel_launch(void* const* d_in, const int* in_sizes, int n_in,
                              void* d_out, int out_size, void* d_ws,
                              size_t ws_size, hipStream_t stream) {
  const int* tokens = (const int*)d_in[0];
  const float* h0 = (const float*)d_in[1];
  const float* c0 = (const float*)d_in[2];
  const float* emb = (const float*)d_in[3];
  const float* W0 = (const float*)d_in[4];
  const float* U0 = (const float*)d_in[5];
  const float* b0 = (const float*)d_in[6];
  const float* W1 = (const float*)d_in[7];
  const float* U1 = (const float*)d_in[8];
  const float* b1 = (const float*)d_in[9];
  const float* gammap = (const float*)d_in[10];
  const float* betap = (const float*)d_in[11];
  const float* mmean = (const float*)d_in[12];
  const float* mvar = (const float*)d_in[13];

  char* ws = (char*)d_ws;
  ushort_t* Uc0 = (ushort_t*)(ws + 0);             //  8 MB slice-frag U0
  ushort_t* Uc1 = (ushort_t*)(ws + 8388608);       //  8 MB slice-frag U1
  ushort_t* W0f = (ushort_t*)(ws + 16777216);      //  2 MB [pc][256]
  ushort_t* W1f = (ushort_t*)(ws + 18874368);      //  8 MB [pc][1024]
  float* bp0 = (float*)(ws + 27262976);            // 16 KB
  float* bp1 = (float*)(ws + 27279360);            // 16 KB
  ushort_t* Xef = (ushort_t*)(ws + 27295744);      //  4 MB [8192][256]
  ushort_t* XW = (ushort_t*)(ws + 31490048);       // 64 MB [8192][4096]
  ushort_t* hall = (ushort_t*)(ws + 98598912);     // 16.5 MB: 129 x 128KB
  float* c_st = (float*)(ws + 115507200);          // 256 KB
  unsigned* bars = (unsigned*)(ws + 115769344);    // 2 KB

  k_convert_u<<<2048, 256, 0, stream>>>(U0, Uc0);
  k_convert_u<<<2048, 256, 0, stream>>>(U1, Uc1);
  k_convert<<<4096, 256, 0, stream>>>(W0, W0f, 8);
  k_convert<<<16384, 256, 0, stream>>>(W1, W1f, 10);
  k_bias<<<16, 256, 0, stream>>>(b0, b1, bp0, bp1);
  k_gather<<<8192, 256, 0, stream>>>(tokens, emb, Xef);
  k_init<<<256, 256, 0, stream>>>(h0, c0, hall, c_st, bars);

  float* outp = (float*)d_out;

  // ---- layer 0 ----
  k_gemm<16, 0><<<2048, 256, 0, stream>>>(Xef, W0f, XW);
  k_pers<0><<<256, 256, 0, stream>>>(Uc0, XW, bp0, hall, c_st, nullptr,
                                     nullptr, nullptr, nullptr, nullptr,
                                     bars);

  // ---- layer 1 (GEMM A = hall slots 1..128 = L0 outputs) ----
  k_gemm<64, 1><<<2048, 256, 0, stream>>>(hall + 65536, W1f, XW);
  k_pers<1><<<256, 256, 0, stream>>>(Uc1, XW, bp1, hall, c_st, outp, gammap,
                                     betap, mmean, mvar, bars + 160);
}